// Round 2
// baseline (759.658 us; speedup 1.0000x reference)
//
#include <hip/hip_runtime.h>
#include <stdint.h>

// Problem constants (fixed by the reference): x is (128,1,512,512) fp32, k=2048.
#define B        128
#define ROW_N    262144                 // 512*512 elements per row
#define NBUCKET  4096                   // 12-bit key buckets
#define KSHIFT   19                     // (bits & 0x7FFFFFFF) >> 19 -> 0..4095
#define CAND_MAX 4096                   // candidate slots per row (expected ~950)
#define CHUNK    8192                   // floats per block in the streaming passes
#define CHUNKS_PER_ROW (ROW_N / CHUNK)  // 32
#define THREADS  256
#define V4_PER_THREAD (CHUNK / 4 / THREADS)  // 8 float4 per thread (in-flight MLP)

// workspace layout (bytes)
#define OFF_HIST 0
#define SZ_HIST  (B * NBUCKET * 4)          // 2 MiB
#define OFF_CNT  (OFF_HIST + SZ_HIST)       // per-row candidate counters (B u32)
#define OFF_BKT  (OFF_CNT + 512)            // per-row threshold bucket (B int)
#define OFF_NEED (OFF_BKT + 512)            // per-row remaining count (B int)
#define OFF_CAND (OFF_NEED + 512)           // B * CAND_MAX * uint2

// ---------------- pass 1: per-row 12-bit histogram of |x| bits ----------------
// 2-way lane-interleaved LDS sub-histograms: entry = h[key*2 + (lane&1)].
// Halves same-address atomic serialization; stride-2 layout still uses all banks.
__global__ __launch_bounds__(THREADS) void hist_kernel(const float* __restrict__ x,
                                                       unsigned* __restrict__ hist) {
    __shared__ unsigned h[NBUCKET * 2];   // 32 KiB
    const int t = threadIdx.x;
    for (int i = t; i < NBUCKET * 2; i += THREADS) h[i] = 0;
    __syncthreads();

    const int row = blockIdx.y;
    const float4* xr = (const float4*)(x + (size_t)row * ROW_N);
    const int base4 = blockIdx.x * (CHUNK / 4);
    const int p = t & 1;

    // batch-load: 8 independent float4 in flight before any use
    float4 r[V4_PER_THREAD];
#pragma unroll
    for (int i = 0; i < V4_PER_THREAD; ++i) r[i] = xr[base4 + i * THREADS + t];

#pragma unroll
    for (int i = 0; i < V4_PER_THREAD; ++i) {
        const float4 v = r[i];
        atomicAdd(&h[(((__float_as_uint(v.x) & 0x7FFFFFFFu) >> KSHIFT) << 1) | p], 1u);
        atomicAdd(&h[(((__float_as_uint(v.y) & 0x7FFFFFFFu) >> KSHIFT) << 1) | p], 1u);
        atomicAdd(&h[(((__float_as_uint(v.z) & 0x7FFFFFFFu) >> KSHIFT) << 1) | p], 1u);
        atomicAdd(&h[(((__float_as_uint(v.w) & 0x7FFFFFFFu) >> KSHIFT) << 1) | p], 1u);
    }
    __syncthreads();

    unsigned* gh = hist + (size_t)row * NBUCKET;
    for (int i = t; i < NBUCKET; i += THREADS) {
        const unsigned c = h[i * 2] + h[i * 2 + 1];
        if (c) atomicAdd(&gh[i], c);   // ~150-300 nonzero buckets/block only
    }
}

// -------- pass 2: per-row suffix scan from the top bucket; find threshold ------
__global__ __launch_bounds__(THREADS) void select_kernel(const unsigned* __restrict__ hist,
                                                         const int* __restrict__ topk,
                                                         int* __restrict__ row_bucket,
                                                         int* __restrict__ row_need) {
    const int row = blockIdx.x;
    const int t = threadIdx.x;
    const unsigned K = (unsigned)(*topk);
    const unsigned* gh = hist + (size_t)row * NBUCKET;

    __shared__ unsigned partial[THREADS];
    __shared__ unsigned excl[THREADS];
    const int PER = NBUCKET / THREADS;  // 16 buckets per thread, descending order
    unsigned s = 0;
#pragma unroll
    for (int i = 0; i < PER; ++i) s += gh[NBUCKET - 1 - (t * PER + i)];
    partial[t] = s;
    __syncthreads();
    if (t == 0) {
        unsigned c = 0;
        for (int i = 0; i < THREADS; ++i) { excl[i] = c; c += partial[i]; }
    }
    __syncthreads();

    unsigned cum = excl[t];
#pragma unroll
    for (int i = 0; i < PER; ++i) {
        const int bucket = NBUCKET - 1 - (t * PER + i);
        const unsigned c = gh[bucket];
        if (cum < K && cum + c >= K) {   // unique crossing thread/iteration
            row_bucket[row] = bucket;
            row_need[row]   = (int)(K - cum);
        }
        cum += c;
    }
}

// ----- pass 3: stream output; collect exact-bucket candidates for tie-break ----
__global__ __launch_bounds__(THREADS) void output_kernel(const float* __restrict__ x,
                                                         float* __restrict__ out,
                                                         const int* __restrict__ row_bucket,
                                                         unsigned* __restrict__ cand_count,
                                                         uint2* __restrict__ cand) {
    const int row = blockIdx.y;
    const int b = row_bucket[row];
    const size_t rowbase = (size_t)row * ROW_N;
    const float4* xr = (const float4*)(x + rowbase);
    float4* outr = (float4*)(out + rowbase);
    const int base4 = blockIdx.x * (CHUNK / 4);
    const int t = threadIdx.x;

    // batch-load: 8 independent float4 in flight
    float4 r[V4_PER_THREAD];
#pragma unroll
    for (int i = 0; i < V4_PER_THREAD; ++i) r[i] = xr[base4 + i * THREADS + t];

#pragma unroll
    for (int i = 0; i < V4_PER_THREAD; ++i) {
        const int i4 = base4 + i * THREADS + t;
        const float4 v = r[i];
        const unsigned bx = __float_as_uint(v.x), by = __float_as_uint(v.y);
        const unsigned bz = __float_as_uint(v.z), bw = __float_as_uint(v.w);
        const int kx = (int)((bx & 0x7FFFFFFFu) >> KSHIFT);
        const int ky = (int)((by & 0x7FFFFFFFu) >> KSHIFT);
        const int kz = (int)((bz & 0x7FFFFFFFu) >> KSHIFT);
        const int kw = (int)((bw & 0x7FFFFFFFu) >> KSHIFT);
        float4 o;
        o.x = (kx > b) ? v.x : 0.0f;
        o.y = (ky > b) ? v.y : 0.0f;
        o.z = (kz > b) ? v.z : 0.0f;
        o.w = (kw > b) ? v.w : 0.0f;
        outr[i4] = o;

        // rare path: exact-bucket candidates; whole wave skips when none present
        const bool has = (kx == b) | (ky == b) | (kz == b) | (kw == b);
        if (__ballot(has)) {
            if (has) {
                const unsigned bits4[4] = {bx, by, bz, bw};
                const int keys4[4] = {kx, ky, kz, kw};
#pragma unroll
                for (int c = 0; c < 4; ++c) {
                    if (keys4[c] == b) {
                        const unsigned pos = atomicAdd(&cand_count[row], 1u);
                        if (pos < CAND_MAX)
                            cand[(size_t)row * CAND_MAX + pos] =
                                make_uint2((unsigned)(i4 * 4 + c), bits4[c]);
                    }
                }
            }
        }
    }
}

// ---- pass 4: exact top-`need` among candidates (desc |x|, asc index on tie) ---
__global__ __launch_bounds__(THREADS) void fixup_kernel(float* __restrict__ out,
                                                        const int* __restrict__ row_need,
                                                        const unsigned* __restrict__ cand_count,
                                                        const uint2* __restrict__ cand) {
    const int row = blockIdx.x;
    const int t = threadIdx.x;
    unsigned cc = cand_count[row];
    const int c = (int)(cc < (unsigned)CAND_MAX ? cc : (unsigned)CAND_MAX);
    const int need = row_need[row];

    __shared__ unsigned sidx[CAND_MAX];   // 16 KiB
    __shared__ unsigned sbits[CAND_MAX];  // 16 KiB
    const uint2* rc = cand + (size_t)row * CAND_MAX;
    for (int i = t; i < c; i += THREADS) {
        uint2 e = rc[i];
        sidx[i] = e.x;
        sbits[i] = e.y;
    }
    __syncthreads();

    const size_t rowbase = (size_t)row * ROW_N;
    for (int i = t; i < c; i += THREADS) {
        const unsigned bits = sbits[i];
        const unsigned idx = sidx[i];
        const uint64_t key =
            ((uint64_t)(bits & 0x7FFFFFFFu) << 32) | (uint64_t)(~idx);
        int rank = 0;
        for (int j = 0; j < c; ++j) {
            const uint64_t kj =
                ((uint64_t)(sbits[j] & 0x7FFFFFFFu) << 32) | (uint64_t)(~sidx[j]);
            rank += (kj > key) ? 1 : 0;
        }
        if (rank < need) out[rowbase + idx] = __uint_as_float(bits);
    }
}

extern "C" void kernel_launch(void* const* d_in, const int* in_sizes, int n_in,
                              void* d_out, int out_size, void* d_ws, size_t ws_size,
                              hipStream_t stream) {
    const float* x = (const float*)d_in[0];
    const int* topk = (const int*)d_in[1];
    float* out = (float*)d_out;
    char* ws = (char*)d_ws;

    unsigned* hist       = (unsigned*)(ws + OFF_HIST);
    unsigned* cand_count = (unsigned*)(ws + OFF_CNT);
    int* row_bucket      = (int*)(ws + OFF_BKT);
    int* row_need        = (int*)(ws + OFF_NEED);
    uint2* cand          = (uint2*)(ws + OFF_CAND);

    // zero histograms + candidate counters (ws is re-poisoned to 0xAA each run)
    hipMemsetAsync(ws, 0, SZ_HIST + 512, stream);

    dim3 grid_stream(CHUNKS_PER_ROW, B);  // 32 x 128 = 4096 blocks
    hist_kernel<<<grid_stream, THREADS, 0, stream>>>(x, hist);
    select_kernel<<<B, THREADS, 0, stream>>>(hist, topk, row_bucket, row_need);
    output_kernel<<<grid_stream, THREADS, 0, stream>>>(x, out, row_bucket, cand_count, cand);
    fixup_kernel<<<B, THREADS, 0, stream>>>(out, row_need, cand_count, cand);
}

// Round 3
// 315.563 us; speedup vs baseline: 2.4073x; 2.4073x over previous
//
#include <hip/hip_runtime.h>
#include <stdint.h>

// Problem constants (fixed by the reference): x is (128,1,512,512) fp32, k=2048.
#define B        128
#define ROW_N    262144                 // 512*512 elements per row
#define NBUCKET  4096                   // 12-bit key buckets
#define KSHIFT   19                     // (bits & 0x7FFFFFFF) >> 19 -> 0..4095
#define CAND_MAX 4096                   // candidate slots per row (expected ~950)
#define THREADS  256
#define BLOCKS_PER_ROW 8
#define BLK_CHUNK (ROW_N / BLOCKS_PER_ROW)   // 32768 floats per block
#define STAGE_F  4096                        // floats staged per iteration (16 KiB)
#define NITER    (BLK_CHUNK / STAGE_F)       // 8
#define CANDS_LDS 1024                       // per-block candidate capacity (mean ~120)

// workspace layout (bytes)
#define OFF_HIST 0
#define SZ_HIST  (B * NBUCKET * 4)          // 2 MiB
#define OFF_CNT  (OFF_HIST + SZ_HIST)       // per-row candidate counters (B u32)
#define OFF_BKT  (OFF_CNT + 512)            // per-row threshold bucket (B int)
#define OFF_NEED (OFF_BKT + 512)            // per-row remaining count (B int)
#define OFF_CAND (OFF_NEED + 512)           // B * CAND_MAX * uint2

// async global->LDS copy, 16 B per lane. LDS dest must be wave-uniform base +
// lane*16 — our mapping (t*4 floats) satisfies this within each wave.
__device__ __forceinline__ void g2l16(const float* g, float* l) {
    __builtin_amdgcn_global_load_lds(
        (const __attribute__((address_space(1))) void*)g,
        (__attribute__((address_space(3))) void*)l, 16, 0, 0);
}

// ---------------- pass 1: per-row 12-bit histogram of |x| bits ----------------
__global__ __launch_bounds__(THREADS) void hist_kernel(const float* __restrict__ x,
                                                       unsigned* __restrict__ hist) {
    __shared__ float stage[STAGE_F];      // 16 KiB staging buffer
    __shared__ unsigned h[NBUCKET];       // 16 KiB histogram
    const int t = threadIdx.x;
    for (int i = t; i < NBUCKET; i += THREADS) h[i] = 0;
    const int row = blockIdx.y;
    const float* src = x + (size_t)row * ROW_N + (size_t)blockIdx.x * BLK_CHUNK;
    __syncthreads();

    for (int it = 0; it < NITER; ++it) {
        const float* s = src + it * STAGE_F;
#pragma unroll
        for (int q = 0; q < 4; ++q)
            g2l16(s + q * 1024 + t * 4, &stage[q * 1024 + t * 4]);
        __syncthreads();   // compiler drains vmcnt(0) here -> staged data valid
#pragma unroll
        for (int q = 0; q < 4; ++q) {
            const float4 v = *(const float4*)&stage[q * 1024 + t * 4];
            atomicAdd(&h[(__float_as_uint(v.x) & 0x7FFFFFFFu) >> KSHIFT], 1u);
            atomicAdd(&h[(__float_as_uint(v.y) & 0x7FFFFFFFu) >> KSHIFT], 1u);
            atomicAdd(&h[(__float_as_uint(v.z) & 0x7FFFFFFFu) >> KSHIFT], 1u);
            atomicAdd(&h[(__float_as_uint(v.w) & 0x7FFFFFFFu) >> KSHIFT], 1u);
        }
        __syncthreads();   // all consumed before next stage overwrites
    }

    unsigned* gh = hist + (size_t)row * NBUCKET;
    for (int i = t; i < NBUCKET; i += THREADS) {
        const unsigned c = h[i];
        if (c) atomicAdd(&gh[i], c);   // only ~200-400 nonzero buckets/block
    }
}

// -------- pass 2: per-row suffix scan from the top bucket; find threshold ------
__global__ __launch_bounds__(THREADS) void select_kernel(const unsigned* __restrict__ hist,
                                                         const int* __restrict__ topk,
                                                         int* __restrict__ row_bucket,
                                                         int* __restrict__ row_need) {
    const int row = blockIdx.x;
    const int t = threadIdx.x;
    const unsigned K = (unsigned)(*topk);
    const unsigned* gh = hist + (size_t)row * NBUCKET;

    __shared__ unsigned partial[THREADS];
    __shared__ unsigned excl[THREADS];
    const int PER = NBUCKET / THREADS;  // 16 buckets per thread, descending order
    unsigned s = 0;
#pragma unroll
    for (int i = 0; i < PER; ++i) s += gh[NBUCKET - 1 - (t * PER + i)];
    partial[t] = s;
    __syncthreads();
    if (t == 0) {
        unsigned c = 0;
        for (int i = 0; i < THREADS; ++i) { excl[i] = c; c += partial[i]; }
    }
    __syncthreads();

    unsigned cum = excl[t];
#pragma unroll
    for (int i = 0; i < PER; ++i) {
        const int bucket = NBUCKET - 1 - (t * PER + i);
        const unsigned c = gh[bucket];
        if (cum < K && cum + c >= K) {   // unique crossing thread/iteration
            row_bucket[row] = bucket;
            row_need[row]   = (int)(K - cum);
        }
        cum += c;
    }
}

// ----- pass 3: stream output; collect exact-bucket candidates in LDS ----------
__global__ __launch_bounds__(THREADS) void output_kernel(const float* __restrict__ x,
                                                         float* __restrict__ out,
                                                         const int* __restrict__ row_bucket,
                                                         unsigned* __restrict__ cand_count,
                                                         uint2* __restrict__ cand) {
    __shared__ float stage[STAGE_F];       // 16 KiB
    __shared__ unsigned cidx[CANDS_LDS];   // 4 KiB
    __shared__ unsigned cbits[CANDS_LDS];  // 4 KiB
    __shared__ unsigned ccnt;
    __shared__ unsigned cbase;
    const int t = threadIdx.x;
    if (t == 0) ccnt = 0;
    const int row = blockIdx.y;
    const int b = row_bucket[row];
    const size_t rowbase = (size_t)row * ROW_N;
    const int chunk0 = blockIdx.x * BLK_CHUNK;
    const float* src = x + rowbase + chunk0;
    float* dst = out + rowbase + chunk0;
    __syncthreads();

    for (int it = 0; it < NITER; ++it) {
        const int ibase = it * STAGE_F;
#pragma unroll
        for (int q = 0; q < 4; ++q)
            g2l16(src + ibase + q * 1024 + t * 4, &stage[q * 1024 + t * 4]);
        __syncthreads();
#pragma unroll
        for (int q = 0; q < 4; ++q) {
            const int off = q * 1024 + t * 4;
            const float4 v = *(const float4*)&stage[off];
            const unsigned bx = __float_as_uint(v.x), by = __float_as_uint(v.y);
            const unsigned bz = __float_as_uint(v.z), bw = __float_as_uint(v.w);
            const int kx = (int)((bx & 0x7FFFFFFFu) >> KSHIFT);
            const int ky = (int)((by & 0x7FFFFFFFu) >> KSHIFT);
            const int kz = (int)((bz & 0x7FFFFFFFu) >> KSHIFT);
            const int kw = (int)((bw & 0x7FFFFFFFu) >> KSHIFT);
            float4 o;
            o.x = (kx > b) ? v.x : 0.0f;
            o.y = (ky > b) ? v.y : 0.0f;
            o.z = (kz > b) ? v.z : 0.0f;
            o.w = (kw > b) ? v.w : 0.0f;
            *(float4*)(dst + ibase + off) = o;

            // rare path: exact-bucket candidates -> LDS (no global atomics here)
            const unsigned bits4[4] = {bx, by, bz, bw};
            const int keys4[4] = {kx, ky, kz, kw};
#pragma unroll
            for (int c = 0; c < 4; ++c) {
                if (keys4[c] == b) {
                    const unsigned p = atomicAdd(&ccnt, 1u);
                    if (p < CANDS_LDS) {
                        cidx[p]  = (unsigned)(chunk0 + ibase + off + c);
                        cbits[p] = bits4[c];
                    }
                }
            }
        }
        __syncthreads();
    }

    // one global atomic per block: reserve a slot range, then copy out
    if (t == 0) {
        unsigned n = ccnt;
        if (n > CANDS_LDS) n = CANDS_LDS;
        ccnt = n;
        cbase = atomicAdd(&cand_count[row], n);
    }
    __syncthreads();
    const unsigned n = ccnt, base = cbase;
    for (unsigned i = (unsigned)t; i < n; i += THREADS) {
        const unsigned gpos = base + i;
        if (gpos < CAND_MAX)
            cand[(size_t)row * CAND_MAX + gpos] = make_uint2(cidx[i], cbits[i]);
    }
}

// ---- pass 4: exact top-`need` among candidates (desc |x|, asc index on tie) ---
__global__ __launch_bounds__(THREADS) void fixup_kernel(float* __restrict__ out,
                                                        const int* __restrict__ row_need,
                                                        const unsigned* __restrict__ cand_count,
                                                        const uint2* __restrict__ cand) {
    const int row = blockIdx.x;
    const int t = threadIdx.x;
    unsigned cc = cand_count[row];
    const int c = (int)(cc < (unsigned)CAND_MAX ? cc : (unsigned)CAND_MAX);
    const int need = row_need[row];

    __shared__ unsigned sidx[CAND_MAX];   // 16 KiB
    __shared__ unsigned sbits[CAND_MAX];  // 16 KiB
    const uint2* rc = cand + (size_t)row * CAND_MAX;
    for (int i = t; i < c; i += THREADS) {
        uint2 e = rc[i];
        sidx[i] = e.x;
        sbits[i] = e.y;
    }
    __syncthreads();

    const size_t rowbase = (size_t)row * ROW_N;
    for (int i = t; i < c; i += THREADS) {
        const unsigned bits = sbits[i];
        const unsigned idx = sidx[i];
        const uint64_t key =
            ((uint64_t)(bits & 0x7FFFFFFFu) << 32) | (uint64_t)(~idx);
        int rank = 0;
        for (int j = 0; j < c; ++j) {
            const uint64_t kj =
                ((uint64_t)(sbits[j] & 0x7FFFFFFFu) << 32) | (uint64_t)(~sidx[j]);
            rank += (kj > key) ? 1 : 0;
        }
        if (rank < need) out[rowbase + idx] = __uint_as_float(bits);
    }
}

extern "C" void kernel_launch(void* const* d_in, const int* in_sizes, int n_in,
                              void* d_out, int out_size, void* d_ws, size_t ws_size,
                              hipStream_t stream) {
    const float* x = (const float*)d_in[0];
    const int* topk = (const int*)d_in[1];
    float* out = (float*)d_out;
    char* ws = (char*)d_ws;

    unsigned* hist       = (unsigned*)(ws + OFF_HIST);
    unsigned* cand_count = (unsigned*)(ws + OFF_CNT);
    int* row_bucket      = (int*)(ws + OFF_BKT);
    int* row_need        = (int*)(ws + OFF_NEED);
    uint2* cand          = (uint2*)(ws + OFF_CAND);

    // zero histograms + candidate counters (ws is re-poisoned to 0xAA each run)
    hipMemsetAsync(ws, 0, SZ_HIST + 512, stream);

    dim3 grid_stream(BLOCKS_PER_ROW, B);  // 8 x 128 = 1024 blocks
    hist_kernel<<<grid_stream, THREADS, 0, stream>>>(x, hist);
    select_kernel<<<B, THREADS, 0, stream>>>(hist, topk, row_bucket, row_need);
    output_kernel<<<grid_stream, THREADS, 0, stream>>>(x, out, row_bucket, cand_count, cand);
    fixup_kernel<<<B, THREADS, 0, stream>>>(out, row_need, cand_count, cand);
}